// Round 12
// baseline (280.286 us; speedup 1.0000x reference)
//
#include <hip/hip_runtime.h>

#define DEV __device__ __forceinline__

typedef __attribute__((ext_vector_type(2))) float f32x2;
typedef __attribute__((ext_vector_type(4))) float f32x4;
typedef __attribute__((ext_vector_type(16))) float f32x16;
typedef __attribute__((ext_vector_type(8))) short bf8v;   // 8 bf16 as shorts (4 VGPR)
typedef __attribute__((ext_vector_type(4))) unsigned short u16x4;
typedef __attribute__((ext_vector_type(8))) unsigned short u16x8;
typedef __attribute__((ext_vector_type(2))) unsigned int u32x2;
typedef __attribute__((ext_vector_type(4))) unsigned int u32x4;

static constexpr int LSEQ = 2048;
static constexpr int DIM  = 1024;
static constexpr int NH   = 16;
static constexpr int DH   = 64;
static constexpr int NB   = 4;
static constexpr int MROWS = NB * LSEQ;   // 8192
// SCALE * log2(e) folded into Q at projection time
static constexpr float QSCALE = 0.18033688011112042f;

DEV unsigned short f2bf(float x) {
  unsigned u = __float_as_uint(x);
  return (unsigned short)((u + 0x7fffu + ((u >> 16) & 1u)) >> 16);
}

DEV unsigned cvt_pk_bf16(float a, float b) {   // D.lo = bf16(a), D.hi = bf16(b)
  unsigned r;
  asm("v_cvt_pk_bf16_f32 %0, %1, %2" : "=v"(r) : "v"(a), "v"(b));
  return r;
}

DEV void pl32swap(unsigned& a, unsigned& b) {  // a.hi32lanes <-> b.lo32lanes
  asm("v_permlane32_swap_b32 %0, %1" : "+v"(a), "+v"(b));
}

DEV float fexp2(float x) {
  float r;
  asm("v_exp_f32 %0, %1" : "=v"(r) : "v"(x));
  return r;
}

DEV float max3(float a, float b, float c) { return fmaxf(fmaxf(a, b), c); }

DEV void gload_lds16(const void* g, void* l) {
  __builtin_amdgcn_global_load_lds((const __attribute__((address_space(1))) void*)g,
                                   (__attribute__((address_space(3))) void*)l, 16, 0, 0);
}

// ---------------- merged prep: tokens cvt | weights cvt | RbX table ----------------
__global__ __launch_bounds__(256) void k_prep(
    const float* __restrict__ tokens, unsigned short* __restrict__ tok_bf,
    const float* __restrict__ w0, const float* __restrict__ w1,
    const float* __restrict__ w2, const float* __restrict__ w3,
    unsigned short* __restrict__ wdst,
    const float* __restrict__ R, const float* __restrict__ beta,
    u16x4* __restrict__ rbx) {
  __shared__ u16x4 lds2[2048];
  const int bid = blockIdx.x;
  const int tid = threadIdx.x;
  if (bid < 4096) {
    int i = (bid * 256 + tid) * 8;
    f32x4 a = *(const f32x4*)(tokens + i);
    f32x4 b = *(const f32x4*)(tokens + i + 4);
    u16x8 o;
    o[0] = f2bf(a[0]); o[1] = f2bf(a[1]); o[2] = f2bf(a[2]); o[3] = f2bf(a[3]);
    o[4] = f2bf(b[0]); o[5] = f2bf(b[1]); o[6] = f2bf(b[2]); o[7] = f2bf(b[3]);
    *(u16x8*)(tok_bf + i) = o;
    return;
  }
  if (bid < 6144) {
    int wb = bid - 4096;
    int r = wb >> 9;
    const float* src = (r == 0) ? w0 : (r == 1) ? w1 : (r == 2) ? w2 : w3;
    int i = ((wb & 511) * 256 + tid) * 8;
    f32x4 a = *(const f32x4*)(src + i);
    f32x4 b = *(const f32x4*)(src + i + 4);
    u16x8 o;
    o[0] = f2bf(a[0]); o[1] = f2bf(a[1]); o[2] = f2bf(a[2]); o[3] = f2bf(a[3]);
    o[4] = f2bf(b[0]); o[5] = f2bf(b[1]); o[6] = f2bf(b[2]); o[7] = f2bf(b[3]);
    *(u16x8*)(wdst + (size_t)r * DIM * DIM + i) = o;
    return;
  }
  // RbX region
  {
    int rb = bid - 6144;                 // [0,512)
    const int q0 = (rb & 15) * 128;
    const int t  = rb >> 4;
    const float b = beta[0];
    #pragma unroll
    for (int it = 0; it < 4; ++it) {
      int ql = it * 32 + (tid >> 3);
      int kl = (tid & 7) * 8;
      const float* src = R + (size_t)(q0 + ql) * 2048 + t * 64 + kl;
      f32x4 v0 = *(const f32x4*)src;
      f32x4 v1 = *(const f32x4*)(src + 4);
      u16x4 qa, qb;
      #pragma unroll
      for (int m = 0; m < 4; ++m) {
        qa[m] = f2bf(exp2f(b * log2f(fmaxf(v0[m], 1e-8f))));
        qb[m] = f2bf(exp2f(b * log2f(fmaxf(v1[m], 1e-8f))));
      }
      int s = kl >> 4, w = (kl >> 3) & 1;
      lds2[(((s * 2 + 0) * 128) + ql) * 2 + w] = qa;
      lds2[(((s * 2 + 1) * 128) + ql) * 2 + w] = qb;
    }
    __syncthreads();
    u16x8* O = (u16x8*)rbx;
    #pragma unroll
    for (int j = 0; j < 4; ++j) {
      int f = j * 256 + tid;
      int r = f >> 7, qrel = f & 127;
      O[(size_t)(t * 8 + r) * 2048 + q0 + qrel] = *(const u16x8*)&lds2[(r * 128 + qrel) * 2];
    }
  }
}

// ---------------- GEMM core: C[128x128] = A[m0..][1024] * B[n0..][1024]^T ----------------
DEV void gemm_core(const unsigned short* __restrict__ A, const unsigned short* __restrict__ Bm,
                   int m0, int n0, unsigned short* As, unsigned short* Bs, f32x4 (*acc)[4]) {
  const int tid = threadIdx.x;
  const int lane = tid & 63, wid = tid >> 6;
  const int g = lane >> 4, lq = lane & 15;
  const int wr = wid >> 1, wc = wid & 1;

  int aoff[2][4], boff[2][4];
  #pragma unroll
  for (int kk = 0; kk < 2; ++kk) {
    #pragma unroll
    for (int t = 0; t < 4; ++t) {
      aoff[kk][t] = (((wr * 64 + t * 16 + lq) * 128 + kk * 64 + g * 16) ^ ((lq & 7) << 4));
      boff[kk][t] = (((wc * 64 + t * 16 + lq) * 128 + kk * 64 + g * 16) ^ ((lq & 7) << 4));
    }
  }

  for (int kt = 0; kt < 16; ++kt) {
    #pragma unroll
    for (int i = 0; i < 4; ++i) {
      int chunk = i * 256 + tid;
      int row = chunk >> 3;
      int cc = (chunk & 7) ^ (row & 7);   // inverse swizzle on global source
      gload_lds16(A + (size_t)(m0 + row) * 1024 + kt * 64 + cc * 8, As + (i * 256 + wid * 64) * 8);
      gload_lds16(Bm + (size_t)(n0 + row) * 1024 + kt * 64 + cc * 8, Bs + (i * 256 + wid * 64) * 8);
    }
    __syncthreads();
    #pragma unroll
    for (int kk = 0; kk < 2; ++kk) {
      bf8v af[4], bfr[4];
      #pragma unroll
      for (int mi = 0; mi < 4; ++mi) af[mi] = *(const bf8v*)((const char*)As + aoff[kk][mi]);
      #pragma unroll
      for (int ni = 0; ni < 4; ++ni) bfr[ni] = *(const bf8v*)((const char*)Bs + boff[kk][ni]);
      #pragma unroll
      for (int mi = 0; mi < 4; ++mi)
        #pragma unroll
        for (int ni = 0; ni < 4; ++ni)
          acc[mi][ni] = __builtin_amdgcn_mfma_f32_16x16x32_bf16(af[mi], bfr[ni], acc[mi][ni], 0, 0, 0);
    }
    __syncthreads();
  }
}

// ---------------- QKV projection ----------------
// K out: KX[bh][t][c=d>>3][kv&63][j=d&7]   (byte = bh*262144 + t*8192 + c*1024 + r*16 + j*2)
// V out: VX[bh][t][c=kv-chunk][d][j=kv&7]  (same chunked form, row = d)
__global__ __launch_bounds__(256) void k_gemm_qkv(
    const unsigned short* __restrict__ A, const unsigned short* __restrict__ W,
    unsigned short* __restrict__ Qb, unsigned short* __restrict__ KX,
    unsigned short* __restrict__ VX) {
  __shared__ unsigned short As[128 * 64];
  __shared__ unsigned short Bs[128 * 64];
  f32x4 acc[4][4];
  f32x4 z = {0.f, 0.f, 0.f, 0.f};
  #pragma unroll
  for (int mi = 0; mi < 4; ++mi)
    #pragma unroll
    for (int ni = 0; ni < 4; ++ni) acc[mi][ni] = z;

  const int m0 = blockIdx.x * 128, n0 = blockIdx.y * 128;
  gemm_core(A, W, m0, n0, As, Bs, acc);

  const int tid = threadIdx.x;
  const int lane = tid & 63, wid = tid >> 6;
  const int g = lane >> 4, lq = lane & 15;
  const int wr = wid >> 1, wc = wid & 1;
  const int region = n0 >> 10;          // 0=Q 1=K 2=V
  const int nrel0 = n0 & 1023;

  if (region == 0) {
    #pragma unroll
    for (int mi = 0; mi < 4; ++mi)
      #pragma unroll
      for (int ni = 0; ni < 4; ++ni) {
        int m = m0 + wr * 64 + mi * 16 + g * 4;
        int n = nrel0 + wc * 64 + ni * 16 + lq;
        int b = m >> 11, l = m & 2047;
        int h = n >> 6, d = n & 63;
        int base = ((b * NH + h) * LSEQ + l) * DH + d;
        #pragma unroll
        for (int r = 0; r < 4; ++r)
          Qb[base + r * DH] = f2bf(acc[mi][ni][r] * QSCALE);
      }
  } else if (region == 1) {
    #pragma unroll
    for (int mi = 0; mi < 4; ++mi)
      #pragma unroll
      for (int ni = 0; ni < 4; ++ni) {
        int m = m0 + wr * 64 + mi * 16 + g * 4;
        int n = nrel0 + wc * 64 + ni * 16 + lq;
        int b = m >> 11, l = m & 2047;
        int h = n >> 6, d = n & 63;
        size_t base = (size_t)(b * NH + h) * 131072 + (l >> 6) * 4096 +
                      (d >> 3) * 512 + (l & 63) * 8 + (d & 7);
        #pragma unroll
        for (int r = 0; r < 4; ++r)
          KX[base + r * 8] = f2bf(acc[mi][ni][r]);
      }
  } else {
    #pragma unroll
    for (int mi = 0; mi < 4; ++mi)
      #pragma unroll
      for (int ni = 0; ni < 4; ++ni) {
        int m = m0 + wr * 64 + mi * 16 + g * 4;
        int n = nrel0 + wc * 64 + ni * 16 + lq;
        int b = m >> 11, l = m & 2047;   // l = kv (4 consecutive via r)
        int h = n >> 6, d = n & 63;
        u16x4 pk;
        #pragma unroll
        for (int r = 0; r < 4; ++r) pk[r] = f2bf(acc[mi][ni][r]);
        size_t idx = (size_t)(b * NH + h) * 131072 + (l >> 6) * 4096 +
                     ((l >> 3) & 7) * 512 + d * 8 + (l & 7);
        *(u16x4*)(VX + idx) = pk;
      }
  }
}

// ---------------- flash attention: chunk-major K/V LDS (0 bank conflicts) ----------------
__global__ __launch_bounds__(256, 4) void k_attn(
    const unsigned short* __restrict__ Qb, const unsigned short* __restrict__ KX,
    const unsigned short* __restrict__ VX, const unsigned short* __restrict__ RbX,
    unsigned short* __restrict__ AO) {
  __shared__ unsigned short Ks[2][64 * 64];
  __shared__ unsigned short Vs[2][64 * 64];
  const int tid = threadIdx.x;
  const int lane = tid & 63, wid = tid >> 6;
  const int l32 = lane & 31, hi = lane >> 5;
  // bijective XCD swizzle: nwg = 1024, 128 per XCD (8 bh x 16 qblk)
  int flat = blockIdx.y * 16 + blockIdx.x;
  int nid = (flat & 7) * 128 + (flat >> 3);
  const int bh = nid >> 4;
  const int q0 = (nid & 15) * 128;
  const int b = bh >> 4, h = bh & 15;
  const char* Kbh = (const char*)KX + (size_t)bh * 262144;
  const char* Vbh = (const char*)VX + (size_t)bh * 262144;
  const int qw = q0 + wid * 32;
  const int q = qw + l32;

  // Q B-fragments
  const unsigned short* Qbh = Qb + (size_t)bh * LSEQ * DH;
  bf8v qf[4];
  #pragma unroll
  for (int s = 0; s < 4; ++s)
    qf[s] = *(const bf8v*)(Qbh + (size_t)q * DH + s * 16 + hi * 8);

  f32x16 oacc[2];
  #pragma unroll
  for (int db = 0; db < 2; ++db)
    #pragma unroll
    for (int r = 0; r < 16; ++r) oacc[db][r] = 0.f;
  float mrun = -__builtin_inff();
  float lrun = 0.f;

  const f32x16 kz = {0.f, 0.f, 0.f, 0.f, 0.f, 0.f, 0.f, 0.f,
                     0.f, 0.f, 0.f, 0.f, 0.f, 0.f, 0.f, 0.f};

  const unsigned rb_off = (unsigned)(hi * 2048 + q) * 16u;
  const int soff = tid * 16;            // linear staging offset (global AND lds)
  const int fbase = hi * 1024 + l32 * 16;  // fragment base; + s*2048 + {kb2|db}*512 imm

  // ---- prologue: stage tile 0 (buf 0), fully linear ----
  gload_lds16(Kbh + soff, (char*)Ks[0] + soff);
  gload_lds16(Kbh + 4096 + soff, (char*)Ks[0] + 4096 + soff);
  gload_lds16(Vbh + soff, (char*)Vs[0] + soff);
  gload_lds16(Vbh + 4096 + soff, (char*)Vs[0] + 4096 + soff);
  __syncthreads();

  auto TILE = [&](int t, int buf, bool pref) {
    const char* rb_t = (const char*)RbX + (size_t)t * 262144;
    u32x4 rrA = *(const u32x4*)(rb_t + rb_off);
    u32x4 rrB = *(const u32x4*)(rb_t + 65536 + rb_off);

    if (pref) {
      const char* Kt = Kbh + (size_t)(t + 1) * 8192;
      const char* Vn = Vbh + (size_t)(t + 1) * 8192;
      gload_lds16(Kt + soff, (char*)Ks[buf ^ 1] + soff);
      gload_lds16(Kt + 4096 + soff, (char*)Ks[buf ^ 1] + 4096 + soff);
      gload_lds16(Vn + soff, (char*)Vs[buf ^ 1] + soff);
      gload_lds16(Vn + 4096 + soff, (char*)Vs[buf ^ 1] + 4096 + soff);
    }

    // ---- S^T = K Q^T : fragment = base + imm (conflict-free contiguous reads) ----
    const char* kb_ = (const char*)Ks[buf] + fbase;
    f32x16 sac[2];
    __builtin_amdgcn_s_setprio(1);
    sac[0] = __builtin_amdgcn_mfma_f32_32x32x16_bf16(*(const bf8v*)(kb_), qf[0], kz, 0, 0, 0);
    sac[1] = __builtin_amdgcn_mfma_f32_32x32x16_bf16(*(const bf8v*)(kb_ + 512), qf[0], kz, 0, 0, 0);
    #pragma unroll
    for (int s = 1; s < 4; ++s) {
      sac[0] = __builtin_amdgcn_mfma_f32_32x32x16_bf16(*(const bf8v*)(kb_ + s * 2048), qf[s], sac[0], 0, 0, 0);
      sac[1] = __builtin_amdgcn_mfma_f32_32x32x16_bf16(*(const bf8v*)(kb_ + s * 2048 + 512), qf[s], sac[1], 0, 0, 0);
    }
    __builtin_amdgcn_s_setprio(0);

    // ---- column max: max3 chains, then 1 shuffle ----
    float mx;
    {
      float c0 = max3(sac[0][0], sac[0][1], sac[0][2]);
      float c1 = max3(sac[0][4], sac[0][5], sac[0][6]);
      float c2 = max3(sac[0][8], sac[0][9], sac[0][10]);
      float c3 = max3(sac[0][12], sac[0][13], sac[0][14]);
      c0 = max3(c0, sac[0][3], sac[1][0]);
      c1 = max3(c1, sac[0][7], sac[1][4]);
      c2 = max3(c2, sac[0][11], sac[1][8]);
      c3 = max3(c3, sac[0][15], sac[1][12]);
      c0 = max3(c0, sac[1][1], sac[1][2]);
      c1 = max3(c1, sac[1][5], sac[1][6]);
      c2 = max3(c2, sac[1][9], sac[1][10]);
      c3 = max3(c3, sac[1][13], sac[1][14]);
      c0 = max3(c0, sac[1][3], c1);
      c2 = max3(c2, sac[1][7], c3);
      mx = max3(c0, c2, fmaxf(sac[1][11], sac[1][15]));
      mx = fmaxf(mx, __shfl_xor(mx, 32));
    }

    // defer-max (T13)
    if (__any(mx > mrun + 8.f)) {
      float mnew = fmaxf(mrun, mx);
      float corr = fexp2(mrun - mnew);
      mrun = mnew;
      lrun *= corr;
      #pragma unroll
      for (int db = 0; db < 2; ++db)
        #pragma unroll
        for (int r = 0; r < 16; ++r) oacc[db][r] *= corr;
    }

    f32x2 m2; m2[0] = mrun; m2[1] = mrun;
    f32x2 ls2; ls2[0] = 0.f; ls2[1] = 0.f;
    const char* vb_ = (const char*)Vs[buf] + fbase;

    // ---- per-16kv slice: packed exp*rb -> pack -> permlane -> PV mfma ----
    auto SLICE = [&](int s, const u32x4& rv) {
      const int blk = s >> 1, r0 = 8 * (s & 1);
      unsigned w[4];
      #pragma unroll
      for (int i = 0; i < 4; ++i) {
        f32x2 sv; sv[0] = sac[blk][r0 + 2 * i]; sv[1] = sac[blk][r0 + 2 * i + 1];
        sv = sv - m2;
        f32x2 pe; pe[0] = fexp2(sv[0]); pe[1] = fexp2(sv[1]);
        f32x2 rf;
        rf[0] = __uint_as_float(rv[i] << 16);
        rf[1] = __uint_as_float(rv[i] & 0xffff0000u);
        pe = pe * rf;
        ls2 = ls2 + pe;
        w[i] = cvt_pk_bf16(pe[0], pe[1]);
      }
      pl32swap(w[0], w[2]);
      pl32swap(w[1], w[3]);
      union { unsigned u[4]; bf8v v; } pf;
      pf.u[0] = w[0]; pf.u[1] = w[1]; pf.u[2] = w[2]; pf.u[3] = w[3];
      oacc[0] = __builtin_amdgcn_mfma_f32_32x32x16_bf16(*(const bf8v*)(vb_ + s * 2048), pf.v, oacc[0], 0, 0, 0);
      oacc[1] = __builtin_amdgcn_mfma_f32_32x32x16_bf16(*(const bf8v*)(vb_ + s * 2048 + 512), pf.v, oacc[1], 0, 0, 0);
    };
    SLICE(0, rrA);
    rrA = *(const u32x4*)(rb_t + 131072 + rb_off);
    SLICE(1, rrB);
    rrB = *(const u32x4*)(rb_t + 196608 + rb_off);
    SLICE(2, rrA);
    SLICE(3, rrB);
    lrun += ls2[0] + ls2[1];
    __syncthreads();
  };

  for (int tp = 0; tp < 16; ++tp) {
    TILE(2 * tp,     0, true);
    TILE(2 * tp + 1, 1, tp != 15);
  }

  // ---- epilogue ----
  lrun += __shfl_xor(lrun, 32);
  float inv = 1.f / lrun;
  #pragma unroll
  for (int db = 0; db < 2; ++db)
    #pragma unroll
    for (int u = 0; u < 4; ++u) {
      u32x2 w;
      w[0] = cvt_pk_bf16(oacc[db][4 * u + 0] * inv, oacc[db][4 * u + 1] * inv);
      w[1] = cvt_pk_bf16(oacc[db][4 * u + 2] * inv, oacc[db][4 * u + 3] * inv);
      int d = db * 32 + u * 8 + hi * 4;
      *(u32x2*)(AO + (size_t)(b * LSEQ + q) * DIM + h * DH + d) = w;
    }
}

// ---------------- output projection + residual ----------------
__global__ __launch_bounds__(256) void k_gemm_proj(
    const unsigned short* __restrict__ A, const unsigned short* __restrict__ W,
    const float* __restrict__ res, float* __restrict__ out) {
  __shared__ unsigned short As[128 * 64];
  __shared__ unsigned short Bs[128 * 64];
  f32x4 acc[4][4];
  f32x4 z = {0.f, 0.f, 0.f, 0.f};
  #pragma unroll
  for (int mi = 0; mi < 4; ++mi)
    #pragma unroll
    for (int ni = 0; ni < 4; ++ni) acc[mi][ni] = z;

  const int m0 = blockIdx.x * 128, n0 = blockIdx.y * 128;
  gemm_core(A, W, m0, n0, As, Bs, acc);

  const int tid = threadIdx.x;
  const int lane = tid & 63, wid = tid >> 6;
  const int g = lane >> 4, lq = lane & 15;
  const int wr = wid >> 1, wc = wid & 1;
  #pragma unroll
  for (int mi = 0; mi < 4; ++mi)
    #pragma unroll
    for (int ni = 0; ni < 4; ++ni) {
      int m = m0 + wr * 64 + mi * 16 + g * 4;
      int n = n0 + wc * 64 + ni * 16 + lq;
      #pragma unroll
      for (int r = 0; r < 4; ++r) {
        int idx = (m + r) * 1024 + n;
        out[idx] = acc[mi][ni][r] + res[idx];
      }
    }
}

// ---------------- in-place LayerNorm on d_out ----------------
__global__ __launch_bounds__(256) void k_ln(float* __restrict__ x,
                                            const float* __restrict__ gamma,
                                            const float* __restrict__ bias) {
  const int row = blockIdx.x;
  const int tid = threadIdx.x;
  float* xr = x + (size_t)row * 1024;
  f32x4 v = *(f32x4*)(xr + tid * 4);
  float s = v[0] + v[1] + v[2] + v[3];
  float ss = v[0] * v[0] + v[1] * v[1] + v[2] * v[2] + v[3] * v[3];
  #pragma unroll
  for (int off = 1; off < 64; off <<= 1) {
    s += __shfl_xor(s, off);
    ss += __shfl_xor(ss, off);
  }
  __shared__ float red[8];
  const int lane = tid & 63, wid = tid >> 6;
  if (lane == 0) { red[wid] = s; red[wid + 4] = ss; }
  __syncthreads();
  s = red[0] + red[1] + red[2] + red[3];
  ss = red[4] + red[5] + red[6] + red[7];
  float mu = s * (1.f / 1024.f);
  float var = ss * (1.f / 1024.f) - mu * mu;
  float rs = rsqrtf(var + 1e-5f);
  f32x4 gm = *(const f32x4*)(gamma + tid * 4);
  f32x4 bi = *(const f32x4*)(bias + tid * 4);
  f32x4 o;
  #pragma unroll
  for (int j = 0; j < 4; ++j) o[j] = (v[j] - mu) * rs * gm[j] + bi[j];
  *(f32x4*)(xr + tid * 4) = o;
}

extern "C" void kernel_launch(void* const* d_in, const int* in_sizes, int n_in,
                              void* d_out, int out_size, void* d_ws, size_t ws_size,
                              hipStream_t stream) {
  const float* tokens = (const float*)d_in[0];
  const float* R      = (const float*)d_in[1];
  const float* Wq     = (const float*)d_in[2];
  const float* Wk     = (const float*)d_in[3];
  const float* Wv     = (const float*)d_in[4];
  const float* Wp     = (const float*)d_in[5];
  const float* beta   = (const float*)d_in[6];
  const float* gamma  = (const float*)d_in[7];
  const float* bias   = (const float*)d_in[8];
  float* out = (float*)d_out;
  char* ws = (char*)d_ws;

  unsigned short* tok_bf = (unsigned short*)(ws);                 // 16,777,216 B
  unsigned short* wqkv   = (unsigned short*)(ws + 16777216);      //  8,388,608 B (Wq,Wk,Wv,Wp)
  u16x4*          rbx    = (u16x4*)(ws + 25165824);               //  8,388,608 B
  unsigned short* qb     = (unsigned short*)(ws + 41943040);      // 16,777,216 B
  unsigned short* kx     = (unsigned short*)(ws + 58720256);      // 16,777,216 B
  unsigned short* vx     = (unsigned short*)(ws + 75497472);      // 16,777,216 B
  unsigned short* wp     = wqkv + 3 * DIM * DIM;
  unsigned short* ao     = tok_bf;  // reuse: tok_bf dead after QKV GEMM

  k_prep<<<6656, 256, 0, stream>>>(tokens, tok_bf, Wq, Wk, Wv, Wp, wqkv, R, beta, rbx);

  k_gemm_qkv<<<dim3(64, 24), 256, 0, stream>>>(tok_bf, wqkv, qb, kx, vx);
  k_attn<<<dim3(16, 64), 256, 0, stream>>>(qb, kx, vx, (const unsigned short*)rbx, ao);
  k_gemm_proj<<<dim3(64, 8), 256, 0, stream>>>(ao, wp, tokens, out);
  k_ln<<<8192, 256, 0, stream>>>(out, gamma, bias);
}

// Round 14
// 229.674 us; speedup vs baseline: 1.2204x; 1.2204x over previous
//
#include <hip/hip_runtime.h>

#define DEV __device__ __forceinline__

typedef __attribute__((ext_vector_type(2))) float f32x2;
typedef __attribute__((ext_vector_type(4))) float f32x4;
typedef __attribute__((ext_vector_type(16))) float f32x16;
typedef __attribute__((ext_vector_type(8))) short bf8v;   // 8 bf16 as shorts (4 VGPR)
typedef __attribute__((ext_vector_type(4))) unsigned short u16x4;
typedef __attribute__((ext_vector_type(8))) unsigned short u16x8;
typedef __attribute__((ext_vector_type(2))) unsigned int u32x2;
typedef __attribute__((ext_vector_type(4))) unsigned int u32x4;

static constexpr int LSEQ = 2048;
static constexpr int DIM  = 1024;
static constexpr int NH   = 16;
static constexpr int DH   = 64;
static constexpr int NB   = 4;
static constexpr int MROWS = NB * LSEQ;   // 8192
// SCALE * log2(e) folded into Q at projection time
static constexpr float QSCALE = 0.18033688011112042f;

DEV unsigned short f2bf(float x) {
  unsigned u = __float_as_uint(x);
  return (unsigned short)((u + 0x7fffu + ((u >> 16) & 1u)) >> 16);
}

DEV unsigned cvt_pk_bf16(float a, float b) {   // D.lo = bf16(a), D.hi = bf16(b)
  unsigned r;
  asm("v_cvt_pk_bf16_f32 %0, %1, %2" : "=v"(r) : "v"(a), "v"(b));
  return r;
}

DEV void pl32swap(unsigned& a, unsigned& b) {  // a.hi32lanes <-> b.lo32lanes
  asm("v_permlane32_swap_b32 %0, %1" : "+v"(a), "+v"(b));
}

DEV float fexp2(float x) {
  float r;
  asm("v_exp_f32 %0, %1" : "=v"(r) : "v"(x));
  return r;
}

DEV float max3(float a, float b, float c) { return fmaxf(fmaxf(a, b), c); }

DEV void gload_lds16(const void* g, void* l) {
  __builtin_amdgcn_global_load_lds((const __attribute__((address_space(1))) void*)g,
                                   (__attribute__((address_space(3))) void*)l, 16, 0, 0);
}

// ---------------- merged prep: tokens cvt | weights cvt | RbX table ----------------
__global__ __launch_bounds__(256) void k_prep(
    const float* __restrict__ tokens, unsigned short* __restrict__ tok_bf,
    const float* __restrict__ w0, const float* __restrict__ w1,
    const float* __restrict__ w2, const float* __restrict__ w3,
    unsigned short* __restrict__ wdst,
    const float* __restrict__ R, const float* __restrict__ beta,
    u16x4* __restrict__ rbx) {
  __shared__ u16x4 lds2[2048];
  const int bid = blockIdx.x;
  const int tid = threadIdx.x;
  if (bid < 4096) {
    int i = (bid * 256 + tid) * 8;
    f32x4 a = *(const f32x4*)(tokens + i);
    f32x4 b = *(const f32x4*)(tokens + i + 4);
    u16x8 o;
    o[0] = f2bf(a[0]); o[1] = f2bf(a[1]); o[2] = f2bf(a[2]); o[3] = f2bf(a[3]);
    o[4] = f2bf(b[0]); o[5] = f2bf(b[1]); o[6] = f2bf(b[2]); o[7] = f2bf(b[3]);
    *(u16x8*)(tok_bf + i) = o;
    return;
  }
  if (bid < 6144) {
    int wb = bid - 4096;
    int r = wb >> 9;
    const float* src = (r == 0) ? w0 : (r == 1) ? w1 : (r == 2) ? w2 : w3;
    int i = ((wb & 511) * 256 + tid) * 8;
    f32x4 a = *(const f32x4*)(src + i);
    f32x4 b = *(const f32x4*)(src + i + 4);
    u16x8 o;
    o[0] = f2bf(a[0]); o[1] = f2bf(a[1]); o[2] = f2bf(a[2]); o[3] = f2bf(a[3]);
    o[4] = f2bf(b[0]); o[5] = f2bf(b[1]); o[6] = f2bf(b[2]); o[7] = f2bf(b[3]);
    *(u16x8*)(wdst + (size_t)r * DIM * DIM + i) = o;
    return;
  }
  // RbX region
  {
    int rb = bid - 6144;                 // [0,512)
    const int q0 = (rb & 15) * 128;
    const int t  = rb >> 4;
    const float b = beta[0];
    #pragma unroll
    for (int it = 0; it < 4; ++it) {
      int ql = it * 32 + (tid >> 3);
      int kl = (tid & 7) * 8;
      const float* src = R + (size_t)(q0 + ql) * 2048 + t * 64 + kl;
      f32x4 v0 = *(const f32x4*)src;
      f32x4 v1 = *(const f32x4*)(src + 4);
      u16x4 qa, qb;
      #pragma unroll
      for (int m = 0; m < 4; ++m) {
        qa[m] = f2bf(exp2f(b * log2f(fmaxf(v0[m], 1e-8f))));
        qb[m] = f2bf(exp2f(b * log2f(fmaxf(v1[m], 1e-8f))));
      }
      int s = kl >> 4, w = (kl >> 3) & 1;
      lds2[(((s * 2 + 0) * 128) + ql) * 2 + w] = qa;
      lds2[(((s * 2 + 1) * 128) + ql) * 2 + w] = qb;
    }
    __syncthreads();
    u16x8* O = (u16x8*)rbx;
    #pragma unroll
    for (int j = 0; j < 4; ++j) {
      int f = j * 256 + tid;
      int r = f >> 7, qrel = f & 127;
      O[(size_t)(t * 8 + r) * 2048 + q0 + qrel] = *(const u16x8*)&lds2[(r * 128 + qrel) * 2];
    }
  }
}

// ---------------- GEMM core: C[128x128] = A[m0..][1024] * B[n0..][1024]^T ----------------
DEV void gemm_core(const unsigned short* __restrict__ A, const unsigned short* __restrict__ Bm,
                   int m0, int n0, unsigned short* As, unsigned short* Bs, f32x4 (*acc)[4]) {
  const int tid = threadIdx.x;
  const int lane = tid & 63, wid = tid >> 6;
  const int g = lane >> 4, lq = lane & 15;
  const int wr = wid >> 1, wc = wid & 1;

  int aoff[2][4], boff[2][4];
  #pragma unroll
  for (int kk = 0; kk < 2; ++kk) {
    #pragma unroll
    for (int t = 0; t < 4; ++t) {
      aoff[kk][t] = (((wr * 64 + t * 16 + lq) * 128 + kk * 64 + g * 16) ^ ((lq & 7) << 4));
      boff[kk][t] = (((wc * 64 + t * 16 + lq) * 128 + kk * 64 + g * 16) ^ ((lq & 7) << 4));
    }
  }

  for (int kt = 0; kt < 16; ++kt) {
    #pragma unroll
    for (int i = 0; i < 4; ++i) {
      int chunk = i * 256 + tid;
      int row = chunk >> 3;
      int cc = (chunk & 7) ^ (row & 7);   // inverse swizzle on global source
      gload_lds16(A + (size_t)(m0 + row) * 1024 + kt * 64 + cc * 8, As + (i * 256 + wid * 64) * 8);
      gload_lds16(Bm + (size_t)(n0 + row) * 1024 + kt * 64 + cc * 8, Bs + (i * 256 + wid * 64) * 8);
    }
    __syncthreads();
    #pragma unroll
    for (int kk = 0; kk < 2; ++kk) {
      bf8v af[4], bfr[4];
      #pragma unroll
      for (int mi = 0; mi < 4; ++mi) af[mi] = *(const bf8v*)((const char*)As + aoff[kk][mi]);
      #pragma unroll
      for (int ni = 0; ni < 4; ++ni) bfr[ni] = *(const bf8v*)((const char*)Bs + boff[kk][ni]);
      #pragma unroll
      for (int mi = 0; mi < 4; ++mi)
        #pragma unroll
        for (int ni = 0; ni < 4; ++ni)
          acc[mi][ni] = __builtin_amdgcn_mfma_f32_16x16x32_bf16(af[mi], bfr[ni], acc[mi][ni], 0, 0, 0);
    }
    __syncthreads();
  }
}

// ---------------- QKV projection (plain grid mapping) ----------------
__global__ __launch_bounds__(256) void k_gemm_qkv(
    const unsigned short* __restrict__ A, const unsigned short* __restrict__ W,
    unsigned short* __restrict__ Qb, unsigned short* __restrict__ Kb,
    unsigned short* __restrict__ Vt) {
  __shared__ unsigned short As[128 * 64];
  __shared__ unsigned short Bs[128 * 64];
  f32x4 acc[4][4];
  f32x4 z = {0.f, 0.f, 0.f, 0.f};
  #pragma unroll
  for (int mi = 0; mi < 4; ++mi)
    #pragma unroll
    for (int ni = 0; ni < 4; ++ni) acc[mi][ni] = z;

  const int m0 = blockIdx.x * 128, n0 = blockIdx.y * 128;
  gemm_core(A, W, m0, n0, As, Bs, acc);

  const int tid = threadIdx.x;
  const int lane = tid & 63, wid = tid >> 6;
  const int g = lane >> 4, lq = lane & 15;
  const int wr = wid >> 1, wc = wid & 1;
  const int region = n0 >> 10;          // 0=Q 1=K 2=V
  const int nrel0 = n0 & 1023;

  if (region < 2) {
    unsigned short* dst = (region == 0) ? Qb : Kb;
    const float sc = (region == 0) ? QSCALE : 1.0f;
    #pragma unroll
    for (int mi = 0; mi < 4; ++mi)
      #pragma unroll
      for (int ni = 0; ni < 4; ++ni) {
        int m = m0 + wr * 64 + mi * 16 + g * 4;
        int n = nrel0 + wc * 64 + ni * 16 + lq;
        int b = m >> 11, l = m & 2047;
        int h = n >> 6, d = n & 63;
        int base = ((b * NH + h) * LSEQ + l) * DH + d;
        #pragma unroll
        for (int r = 0; r < 4; ++r)
          dst[base + r * DH] = f2bf(acc[mi][ni][r] * sc);
      }
  } else {
    #pragma unroll
    for (int mi = 0; mi < 4; ++mi)
      #pragma unroll
      for (int ni = 0; ni < 4; ++ni) {
        int m = m0 + wr * 64 + mi * 16 + g * 4;
        int n = nrel0 + wc * 64 + ni * 16 + lq;
        int b = m >> 11, l = m & 2047;
        int h = n >> 6, d = n & 63;
        u16x4 pk;
        #pragma unroll
        for (int r = 0; r < 4; ++r) pk[r] = f2bf(acc[mi][ni][r]);
        *(u16x4*)(Vt + (size_t)((b * NH + h) * DH + d) * LSEQ + l) = pk;  // V transposed
      }
  }
}

// ---------------- flash attention: 32x32 MFMA, P in registers, LDS dbuf ----------------
// XCD swizzle groups all 16 q-blocks of a bh on one XCD -> K/V L2-resident.
__global__ __launch_bounds__(256, 4) void k_attn(
    const unsigned short* __restrict__ Qb, const unsigned short* __restrict__ Kb,
    const unsigned short* __restrict__ Vt, const unsigned short* __restrict__ RbX,
    unsigned short* __restrict__ AO) {
  __shared__ unsigned short Ks[2][64 * 64];
  __shared__ unsigned short Vs[2][64 * 64];
  const int tid = threadIdx.x;
  const int lane = tid & 63, wid = tid >> 6;
  const int l32 = lane & 31, hi = lane >> 5;
  // bijective XCD swizzle: nwg = 1024, 128 per XCD (8 bh x 16 qblk)
  int flat = blockIdx.y * 16 + blockIdx.x;
  int nid = (flat & 7) * 128 + (flat >> 3);
  const int bh = nid >> 4;
  const int q0 = (nid & 15) * 128;
  const int b = bh >> 4, h = bh & 15;
  const char* Kbh = (const char*)(Kb + (size_t)bh * LSEQ * DH);
  const char* Vbh = (const char*)(Vt + (size_t)bh * DH * LSEQ);
  const int qw = q0 + wid * 32;
  const int q = qw + l32;

  // Q B-fragments
  const unsigned short* Qbh = Qb + (size_t)bh * LSEQ * DH;
  bf8v qf[4];
  #pragma unroll
  for (int s = 0; s < 4; ++s)
    qf[s] = *(const bf8v*)(Qbh + (size_t)q * DH + s * 16 + hi * 8);

  f32x16 oacc[2];
  #pragma unroll
  for (int db = 0; db < 2; ++db)
    #pragma unroll
    for (int r = 0; r < 16; ++r) oacc[db][r] = 0.f;
  float mrun = -__builtin_inff();
  float lrun = 0.f;

  const f32x16 kz = {0.f, 0.f, 0.f, 0.f, 0.f, 0.f, 0.f, 0.f,
                     0.f, 0.f, 0.f, 0.f, 0.f, 0.f, 0.f, 0.f};

  const unsigned rb_off = (unsigned)(hi * 2048 + q) * 16u;
  int koff, voff, ldso;
  {
    int row = tid >> 3;
    int cc = (tid & 7) ^ (row & 7);
    koff = row * (DH * 2) + cc * 16;
    voff = row * (LSEQ * 2) + cc * 16;
    ldso = (wid * 64) * 16;
  }

  // ---- prologue: stage tile 0 (buf 0) ----
  gload_lds16(Kbh + koff, (char*)Ks[0] + ldso);
  gload_lds16(Kbh + koff + 4096, (char*)Ks[0] + ldso + 4096);
  gload_lds16(Vbh + voff, (char*)Vs[0] + ldso);
  gload_lds16(Vbh + voff + 131072, (char*)Vs[0] + ldso + 4096);
  __syncthreads();

  auto TILE = [&](int t, int buf, bool pref) {
    const char* rb_t = (const char*)RbX + (size_t)t * 262144;
    u32x4 rrA = *(const u32x4*)(rb_t + rb_off);
    u32x4 rrB = *(const u32x4*)(rb_t + 65536 + rb_off);

    if (pref) {
      const char* Kt = Kbh + (size_t)(t + 1) * (64 * DH * 2);
      const char* Vn = Vbh + (size_t)(t + 1) * (64 * 2);
      gload_lds16(Kt + koff, (char*)Ks[buf ^ 1] + ldso);
      gload_lds16(Kt + koff + 4096, (char*)Ks[buf ^ 1] + ldso + 4096);
      gload_lds16(Vn + voff, (char*)Vs[buf ^ 1] + ldso);
      gload_lds16(Vn + voff + 131072, (char*)Vs[buf ^ 1] + ldso + 4096);
    }

    // ---- S^T = K Q^T : first MFMA consumes shared zero C ----
    f32x16 sac[2];
    __builtin_amdgcn_s_setprio(1);
    {
      int r0 = l32, r1 = 32 + l32;
      bf8v kf0 = *(const bf8v*)((const char*)Ks[buf] + ((r0 * 128 + hi * 16) ^ ((r0 & 7) << 4)));
      bf8v kf1 = *(const bf8v*)((const char*)Ks[buf] + ((r1 * 128 + hi * 16) ^ ((r1 & 7) << 4)));
      sac[0] = __builtin_amdgcn_mfma_f32_32x32x16_bf16(kf0, qf[0], kz, 0, 0, 0);
      sac[1] = __builtin_amdgcn_mfma_f32_32x32x16_bf16(kf1, qf[0], kz, 0, 0, 0);
    }
    #pragma unroll
    for (int s = 1; s < 4; ++s) {
      #pragma unroll
      for (int kb2 = 0; kb2 < 2; ++kb2) {
        int row = kb2 * 32 + l32;
        bf8v kf = *(const bf8v*)((const char*)Ks[buf] +
                   ((row * 128 + s * 32 + hi * 16) ^ ((row & 7) << 4)));
        sac[kb2] = __builtin_amdgcn_mfma_f32_32x32x16_bf16(kf, qf[s], sac[kb2], 0, 0, 0);
      }
    }
    __builtin_amdgcn_s_setprio(0);

    // ---- column max: max3 chains, then 1 shuffle ----
    float mx;
    {
      float c0 = max3(sac[0][0], sac[0][1], sac[0][2]);
      float c1 = max3(sac[0][4], sac[0][5], sac[0][6]);
      float c2 = max3(sac[0][8], sac[0][9], sac[0][10]);
      float c3 = max3(sac[0][12], sac[0][13], sac[0][14]);
      c0 = max3(c0, sac[0][3], sac[1][0]);
      c1 = max3(c1, sac[0][7], sac[1][4]);
      c2 = max3(c2, sac[0][11], sac[1][8]);
      c3 = max3(c3, sac[0][15], sac[1][12]);
      c0 = max3(c0, sac[1][1], sac[1][2]);
      c1 = max3(c1, sac[1][5], sac[1][6]);
      c2 = max3(c2, sac[1][9], sac[1][10]);
      c3 = max3(c3, sac[1][13], sac[1][14]);
      c0 = max3(c0, sac[1][3], c1);
      c2 = max3(c2, sac[1][7], c3);
      mx = max3(c0, c2, fmaxf(sac[1][11], sac[1][15]));
      mx = fmaxf(mx, __shfl_xor(mx, 32));
    }

    // defer-max (T13)
    if (__any(mx > mrun + 8.f)) {
      float mnew = fmaxf(mrun, mx);
      float corr = fexp2(mrun - mnew);
      mrun = mnew;
      lrun *= corr;
      #pragma unroll
      for (int db = 0; db < 2; ++db)
        #pragma unroll
        for (int r = 0; r < 16; ++r) oacc[db][r] *= corr;
    }

    f32x2 m2; m2[0] = mrun; m2[1] = mrun;
    f32x2 ls2; ls2[0] = 0.f; ls2[1] = 0.f;

    // ---- per-16kv slice: packed exp*rb -> pack -> permlane -> PV mfma ----
    auto SLICE = [&](int s, const u32x4& rv) {
      const int blk = s >> 1, r0 = 8 * (s & 1);
      unsigned w[4];
      #pragma unroll
      for (int i = 0; i < 4; ++i) {
        f32x2 sv; sv[0] = sac[blk][r0 + 2 * i]; sv[1] = sac[blk][r0 + 2 * i + 1];
        sv = sv - m2;
        f32x2 pe; pe[0] = fexp2(sv[0]); pe[1] = fexp2(sv[1]);
        f32x2 rf;
        rf[0] = __uint_as_float(rv[i] << 16);
        rf[1] = __uint_as_float(rv[i] & 0xffff0000u);
        pe = pe * rf;
        ls2 = ls2 + pe;
        w[i] = cvt_pk_bf16(pe[0], pe[1]);
      }
      pl32swap(w[0], w[2]);
      pl32swap(w[1], w[3]);
      union { unsigned u[4]; bf8v v; } pf;
      pf.u[0] = w[0]; pf.u[1] = w[1]; pf.u[2] = w[2]; pf.u[3] = w[3];
      #pragma unroll
      for (int db = 0; db < 2; ++db) {
        int row = db * 32 + l32;
        bf8v vf = *(const bf8v*)((const char*)Vs[buf] +
                   ((row * 128 + s * 32 + hi * 16) ^ ((row & 7) << 4)));
        oacc[db] = __builtin_amdgcn_mfma_f32_32x32x16_bf16(vf, pf.v, oacc[db], 0, 0, 0);
      }
    };
    SLICE(0, rrA);
    rrA = *(const u32x4*)(rb_t + 131072 + rb_off);
    SLICE(1, rrB);
    rrB = *(const u32x4*)(rb_t + 196608 + rb_off);
    SLICE(2, rrA);
    SLICE(3, rrB);
    lrun += ls2[0] + ls2[1];
    __syncthreads();
  };

  for (int tp = 0; tp < 16; ++tp) {
    TILE(2 * tp,     0, true);
    TILE(2 * tp + 1, 1, tp != 15);
  }

  // ---- epilogue ----
  lrun += __shfl_xor(lrun, 32);
  float inv = 1.f / lrun;
  #pragma unroll
  for (int db = 0; db < 2; ++db)
    #pragma unroll
    for (int u = 0; u < 4; ++u) {
      u32x2 w;
      w[0] = cvt_pk_bf16(oacc[db][4 * u + 0] * inv, oacc[db][4 * u + 1] * inv);
      w[1] = cvt_pk_bf16(oacc[db][4 * u + 2] * inv, oacc[db][4 * u + 3] * inv);
      int d = db * 32 + u * 8 + hi * 4;
      *(u32x2*)(AO + (size_t)(b * LSEQ + q) * DIM + h * DH + d) = w;
    }
}

// ---------------- output projection + residual (plain grid mapping) ----------------
__global__ __launch_bounds__(256) void k_gemm_proj(
    const unsigned short* __restrict__ A, const unsigned short* __restrict__ W,
    const float* __restrict__ res, float* __restrict__ out) {
  __shared__ unsigned short As[128 * 64];
  __shared__ unsigned short Bs[128 * 64];
  f32x4 acc[4][4];
  f32x4 z = {0.f, 0.f, 0.f, 0.f};
  #pragma unroll
  for (int mi = 0; mi < 4; ++mi)
    #pragma unroll
    for (int ni = 0; ni < 4; ++ni) acc[mi][ni] = z;

  const int m0 = blockIdx.x * 128, n0 = blockIdx.y * 128;
  gemm_core(A, W, m0, n0, As, Bs, acc);

  const int tid = threadIdx.x;
  const int lane = tid & 63, wid = tid >> 6;
  const int g = lane >> 4, lq = lane & 15;
  const int wr = wid >> 1, wc = wid & 1;
  #pragma unroll
  for (int mi = 0; mi < 4; ++mi)
    #pragma unroll
    for (int ni = 0; ni < 4; ++ni) {
      int m = m0 + wr * 64 + mi * 16 + g * 4;
      int n = n0 + wc * 64 + ni * 16 + lq;
      #pragma unroll
      for (int r = 0; r < 4; ++r) {
        int idx = (m + r) * 1024 + n;
        out[idx] = acc[mi][ni][r] + res[idx];
      }
    }
}

// ---------------- in-place LayerNorm on d_out ----------------
__global__ __launch_bounds__(256) void k_ln(float* __restrict__ x,
                                            const float* __restrict__ gamma,
                                            const float* __restrict__ bias) {
  const int row = blockIdx.x;
  const int tid = threadIdx.x;
  float* xr = x + (size_t)row * 1024;
  f32x4 v = *(f32x4*)(xr + tid * 4);
  float s = v[0] + v[1] + v[2] + v[3];
  float ss = v[0] * v[0] + v[1] * v[1] + v[2] * v[2] + v[3] * v[3];
  #pragma unroll
  for (int off = 1; off < 64; off <<= 1) {
    s += __shfl_xor(s, off);
    ss += __shfl_xor(ss, off);
  }
  __shared__ float red[8];
  const int lane = tid & 63, wid = tid >> 6;
  if (lane == 0) { red[wid] = s; red[wid + 4] = ss; }
  __syncthreads();
  s = red[0] + red[1] + red[2] + red[3];
  ss = red[4] + red[5] + red[6] + red[7];
  float mu = s * (1.f / 1024.f);
  float var = ss * (1.f / 1024.f) - mu * mu;
  float rs = rsqrtf(var + 1e-5f);
  f32x4 gm = *(const f32x4*)(gamma + tid * 4);
  f32x4 bi = *(const f32x4*)(bias + tid * 4);
  f32x4 o;
  #pragma unroll
  for (int j = 0; j < 4; ++j) o[j] = (v[j] - mu) * rs * gm[j] + bi[j];
  *(f32x4*)(xr + tid * 4) = o;
}

extern "C" void kernel_launch(void* const* d_in, const int* in_sizes, int n_in,
                              void* d_out, int out_size, void* d_ws, size_t ws_size,
                              hipStream_t stream) {
  const float* tokens = (const float*)d_in[0];
  const float* R      = (const float*)d_in[1];
  const float* Wq     = (const float*)d_in[2];
  const float* Wk     = (const float*)d_in[3];
  const float* Wv     = (const float*)d_in[4];
  const float* Wp     = (const float*)d_in[5];
  const float* beta   = (const float*)d_in[6];
  const float* gamma  = (const float*)d_in[7];
  const float* bias   = (const float*)d_in[8];
  float* out = (float*)d_out;
  char* ws = (char*)d_ws;

  unsigned short* tok_bf = (unsigned short*)(ws);                 // 16,777,216 B
  unsigned short* wqkv   = (unsigned short*)(ws + 16777216);      //  8,388,608 B (Wq,Wk,Wv,Wp)
  u16x4*          rbx    = (u16x4*)(ws + 25165824);               //  8,388,608 B
  unsigned short* qb     = (unsigned short*)(ws + 41943040);      // 16,777,216 B
  unsigned short* kb     = (unsigned short*)(ws + 58720256);      // 16,777,216 B
  unsigned short* vt     = (unsigned short*)(ws + 75497472);      // 16,777,216 B
  unsigned short* wp     = wqkv + 3 * DIM * DIM;
  unsigned short* ao     = tok_bf;  // reuse: tok_bf dead after QKV GEMM

  k_prep<<<6656, 256, 0, stream>>>(tokens, tok_bf, Wq, Wk, Wv, Wp, wqkv, R, beta, rbx);

  k_gemm_qkv<<<dim3(64, 24), 256, 0, stream>>>(tok_bf, wqkv, qb, kb, vt);
  k_attn<<<dim3(16, 64), 256, 0, stream>>>(qb, kb, vt, (const unsigned short*)rbx, ao);
  k_gemm_proj<<<dim3(64, 8), 256, 0, stream>>>(ao, wp, tokens, out);
  k_ln<<<8192, 256, 0, stream>>>(out, gamma, bias);
}

// Round 15
// 229.155 us; speedup vs baseline: 1.2231x; 1.0023x over previous
//
#include <hip/hip_runtime.h>

#define DEV __device__ __forceinline__

typedef __attribute__((ext_vector_type(2))) float f32x2;
typedef __attribute__((ext_vector_type(4))) float f32x4;
typedef __attribute__((ext_vector_type(16))) float f32x16;
typedef __attribute__((ext_vector_type(8))) short bf8v;   // 8 bf16 as shorts (4 VGPR)
typedef __attribute__((ext_vector_type(4))) unsigned short u16x4;
typedef __attribute__((ext_vector_type(8))) unsigned short u16x8;
typedef __attribute__((ext_vector_type(2))) unsigned int u32x2;
typedef __attribute__((ext_vector_type(4))) unsigned int u32x4;

static constexpr int LSEQ = 2048;
static constexpr int DIM  = 1024;
static constexpr int NH   = 16;
static constexpr int DH   = 64;
static constexpr int NB   = 4;
static constexpr int MROWS = NB * LSEQ;   // 8192
// SCALE * log2(e) folded into Q at projection time
static constexpr float QSCALE = 0.18033688011112042f;

DEV unsigned short f2bf(float x) {
  unsigned u = __float_as_uint(x);
  return (unsigned short)((u + 0x7fffu + ((u >> 16) & 1u)) >> 16);
}

DEV unsigned cvt_pk_bf16(float a, float b) {   // D.lo = bf16(a), D.hi = bf16(b)
  unsigned r;
  asm("v_cvt_pk_bf16_f32 %0, %1, %2" : "=v"(r) : "v"(a), "v"(b));
  return r;
}

DEV void pl32swap(unsigned& a, unsigned& b) {  // a.hi32lanes <-> b.lo32lanes
  asm("v_permlane32_swap_b32 %0, %1" : "+v"(a), "+v"(b));
}

DEV float fexp2(float x) {
  float r;
  asm("v_exp_f32 %0, %1" : "=v"(r) : "v"(x));
  return r;
}

DEV float max3(float a, float b, float c) { return fmaxf(fmaxf(a, b), c); }

DEV void gload_lds16(const void* g, void* l) {
  __builtin_amdgcn_global_load_lds((const __attribute__((address_space(1))) void*)g,
                                   (__attribute__((address_space(3))) void*)l, 16, 0, 0);
}

// ---------------- merged prep: tokens cvt | weights cvt | RbX table ----------------
__global__ __launch_bounds__(256) void k_prep(
    const float* __restrict__ tokens, unsigned short* __restrict__ tok_bf,
    const float* __restrict__ w0, const float* __restrict__ w1,
    const float* __restrict__ w2, const float* __restrict__ w3,
    unsigned short* __restrict__ wdst,
    const float* __restrict__ R, const float* __restrict__ beta,
    u16x4* __restrict__ rbx) {
  __shared__ u16x4 lds2[2048];
  const int bid = blockIdx.x;
  const int tid = threadIdx.x;
  if (bid < 4096) {
    int i = (bid * 256 + tid) * 8;
    f32x4 a = *(const f32x4*)(tokens + i);
    f32x4 b = *(const f32x4*)(tokens + i + 4);
    u16x8 o;
    o[0] = f2bf(a[0]); o[1] = f2bf(a[1]); o[2] = f2bf(a[2]); o[3] = f2bf(a[3]);
    o[4] = f2bf(b[0]); o[5] = f2bf(b[1]); o[6] = f2bf(b[2]); o[7] = f2bf(b[3]);
    *(u16x8*)(tok_bf + i) = o;
    return;
  }
  if (bid < 6144) {
    int wb = bid - 4096;
    int r = wb >> 9;
    const float* src = (r == 0) ? w0 : (r == 1) ? w1 : (r == 2) ? w2 : w3;
    int i = ((wb & 511) * 256 + tid) * 8;
    f32x4 a = *(const f32x4*)(src + i);
    f32x4 b = *(const f32x4*)(src + i + 4);
    u16x8 o;
    o[0] = f2bf(a[0]); o[1] = f2bf(a[1]); o[2] = f2bf(a[2]); o[3] = f2bf(a[3]);
    o[4] = f2bf(b[0]); o[5] = f2bf(b[1]); o[6] = f2bf(b[2]); o[7] = f2bf(b[3]);
    *(u16x8*)(wdst + (size_t)r * DIM * DIM + i) = o;
    return;
  }
  // RbX region
  {
    int rb = bid - 6144;                 // [0,512)
    const int q0 = (rb & 15) * 128;
    const int t  = rb >> 4;
    const float b = beta[0];
    #pragma unroll
    for (int it = 0; it < 4; ++it) {
      int ql = it * 32 + (tid >> 3);
      int kl = (tid & 7) * 8;
      const float* src = R + (size_t)(q0 + ql) * 2048 + t * 64 + kl;
      f32x4 v0 = *(const f32x4*)src;
      f32x4 v1 = *(const f32x4*)(src + 4);
      u16x4 qa, qb;
      #pragma unroll
      for (int m = 0; m < 4; ++m) {
        qa[m] = f2bf(exp2f(b * log2f(fmaxf(v0[m], 1e-8f))));
        qb[m] = f2bf(exp2f(b * log2f(fmaxf(v1[m], 1e-8f))));
      }
      int s = kl >> 4, w = (kl >> 3) & 1;
      lds2[(((s * 2 + 0) * 128) + ql) * 2 + w] = qa;
      lds2[(((s * 2 + 1) * 128) + ql) * 2 + w] = qb;
    }
    __syncthreads();
    u16x8* O = (u16x8*)rbx;
    #pragma unroll
    for (int j = 0; j < 4; ++j) {
      int f = j * 256 + tid;
      int r = f >> 7, qrel = f & 127;
      O[(size_t)(t * 8 + r) * 2048 + q0 + qrel] = *(const u16x8*)&lds2[(r * 128 + qrel) * 2];
    }
  }
}

// ---------------- GEMM core: C[128x128] = A[m0..][1024] * B[n0..][1024]^T ----------------
DEV void gemm_core(const unsigned short* __restrict__ A, const unsigned short* __restrict__ Bm,
                   int m0, int n0, unsigned short* As, unsigned short* Bs, f32x4 (*acc)[4]) {
  const int tid = threadIdx.x;
  const int lane = tid & 63, wid = tid >> 6;
  const int g = lane >> 4, lq = lane & 15;
  const int wr = wid >> 1, wc = wid & 1;

  int aoff[2][4], boff[2][4];
  #pragma unroll
  for (int kk = 0; kk < 2; ++kk) {
    #pragma unroll
    for (int t = 0; t < 4; ++t) {
      aoff[kk][t] = (((wr * 64 + t * 16 + lq) * 128 + kk * 64 + g * 16) ^ ((lq & 7) << 4));
      boff[kk][t] = (((wc * 64 + t * 16 + lq) * 128 + kk * 64 + g * 16) ^ ((lq & 7) << 4));
    }
  }

  for (int kt = 0; kt < 16; ++kt) {
    #pragma unroll
    for (int i = 0; i < 4; ++i) {
      int chunk = i * 256 + tid;
      int row = chunk >> 3;
      int cc = (chunk & 7) ^ (row & 7);   // inverse swizzle on global source
      gload_lds16(A + (size_t)(m0 + row) * 1024 + kt * 64 + cc * 8, As + (i * 256 + wid * 64) * 8);
      gload_lds16(Bm + (size_t)(n0 + row) * 1024 + kt * 64 + cc * 8, Bs + (i * 256 + wid * 64) * 8);
    }
    __syncthreads();
    #pragma unroll
    for (int kk = 0; kk < 2; ++kk) {
      bf8v af[4], bfr[4];
      #pragma unroll
      for (int mi = 0; mi < 4; ++mi) af[mi] = *(const bf8v*)((const char*)As + aoff[kk][mi]);
      #pragma unroll
      for (int ni = 0; ni < 4; ++ni) bfr[ni] = *(const bf8v*)((const char*)Bs + boff[kk][ni]);
      #pragma unroll
      for (int mi = 0; mi < 4; ++mi)
        #pragma unroll
        for (int ni = 0; ni < 4; ++ni)
          acc[mi][ni] = __builtin_amdgcn_mfma_f32_16x16x32_bf16(af[mi], bfr[ni], acc[mi][ni], 0, 0, 0);
    }
    __syncthreads();
  }
}

// ---------------- QKV projection (Q/K epilogue via LDS bounce -> coalesced u16x8) ----
__global__ __launch_bounds__(256) void k_gemm_qkv(
    const unsigned short* __restrict__ A, const unsigned short* __restrict__ W,
    unsigned short* __restrict__ Qb, unsigned short* __restrict__ Kb,
    unsigned short* __restrict__ Vt) {
  __shared__ unsigned short sbuf[128 * 136];   // 34816 B: staging (As+Bs) and C-tile bounce
  unsigned short* As = sbuf;
  unsigned short* Bs = sbuf + 128 * 64;
  f32x4 acc[4][4];
  f32x4 z = {0.f, 0.f, 0.f, 0.f};
  #pragma unroll
  for (int mi = 0; mi < 4; ++mi)
    #pragma unroll
    for (int ni = 0; ni < 4; ++ni) acc[mi][ni] = z;

  const int m0 = blockIdx.x * 128, n0 = blockIdx.y * 128;
  gemm_core(A, W, m0, n0, As, Bs, acc);

  const int tid = threadIdx.x;
  const int lane = tid & 63, wid = tid >> 6;
  const int g = lane >> 4, lq = lane & 15;
  const int wr = wid >> 1, wc = wid & 1;
  const int region = n0 >> 10;          // 0=Q 1=K 2=V
  const int nrel0 = n0 & 1023;

  if (region < 2) {
    unsigned short* dst = (region == 0) ? Qb : Kb;
    const float sc = (region == 0) ? QSCALE : 1.0f;
    // bounce: acc -> LDS [m_local][n_local] (pad row to 136 u16: 2-way banks, free)
    #pragma unroll
    for (int mi = 0; mi < 4; ++mi)
      #pragma unroll
      for (int ni = 0; ni < 4; ++ni) {
        int ml = wr * 64 + mi * 16 + g * 4;
        int nl = wc * 64 + ni * 16 + lq;
        #pragma unroll
        for (int r = 0; r < 4; ++r)
          sbuf[(ml + r) * 136 + nl] = f2bf(acc[mi][ni][r] * sc);
      }
    __syncthreads();
    // coalesced read-out: 8 x (ds_read u16x8 + 16B global store, 128B/16-lane segments)
    #pragma unroll
    for (int j = 0; j < 8; ++j) {
      int idx = j * 256 + tid;
      int ml = idx >> 4, nl = (idx & 15) * 8;
      u16x8 v = *(const u16x8*)&sbuf[ml * 136 + nl];
      int m = m0 + ml, n = nrel0 + nl;
      int b = m >> 11, l = m & 2047;
      int h = n >> 6, d = n & 63;
      *(u16x8*)(dst + (size_t)((b * NH + h) * LSEQ + l) * DH + d) = v;
    }
  } else {
    #pragma unroll
    for (int mi = 0; mi < 4; ++mi)
      #pragma unroll
      for (int ni = 0; ni < 4; ++ni) {
        int m = m0 + wr * 64 + mi * 16 + g * 4;
        int n = nrel0 + wc * 64 + ni * 16 + lq;
        int b = m >> 11, l = m & 2047;
        int h = n >> 6, d = n & 63;
        u16x4 pk;
        #pragma unroll
        for (int r = 0; r < 4; ++r) pk[r] = f2bf(acc[mi][ni][r]);
        *(u16x4*)(Vt + (size_t)((b * NH + h) * DH + d) * LSEQ + l) = pk;  // V transposed
      }
  }
}

// ---------------- flash attention: 32x32 MFMA, P in registers, LDS dbuf ----------------
// XCD swizzle groups all 16 q-blocks of a bh on one XCD -> K/V L2-resident.
__global__ __launch_bounds__(256, 4) void k_attn(
    const unsigned short* __restrict__ Qb, const unsigned short* __restrict__ Kb,
    const unsigned short* __restrict__ Vt, const unsigned short* __restrict__ RbX,
    unsigned short* __restrict__ AO) {
  __shared__ unsigned short Ks[2][64 * 64];
  __shared__ unsigned short Vs[2][64 * 64];
  const int tid = threadIdx.x;
  const int lane = tid & 63, wid = tid >> 6;
  const int l32 = lane & 31, hi = lane >> 5;
  // bijective XCD swizzle: nwg = 1024, 128 per XCD (8 bh x 16 qblk)
  int flat = blockIdx.y * 16 + blockIdx.x;
  int nid = (flat & 7) * 128 + (flat >> 3);
  const int bh = nid >> 4;
  const int q0 = (nid & 15) * 128;
  const int b = bh >> 4, h = bh & 15;
  const char* Kbh = (const char*)(Kb + (size_t)bh * LSEQ * DH);
  const char* Vbh = (const char*)(Vt + (size_t)bh * DH * LSEQ);
  const int qw = q0 + wid * 32;
  const int q = qw + l32;

  // Q B-fragments
  const unsigned short* Qbh = Qb + (size_t)bh * LSEQ * DH;
  bf8v qf[4];
  #pragma unroll
  for (int s = 0; s < 4; ++s)
    qf[s] = *(const bf8v*)(Qbh + (size_t)q * DH + s * 16 + hi * 8);

  f32x16 oacc[2];
  #pragma unroll
  for (int db = 0; db < 2; ++db)
    #pragma unroll
    for (int r = 0; r < 16; ++r) oacc[db][r] = 0.f;
  float mrun = -__builtin_inff();
  float lrun = 0.f;

  const f32x16 kz = {0.f, 0.f, 0.f, 0.f, 0.f, 0.f, 0.f, 0.f,
                     0.f, 0.f, 0.f, 0.f, 0.f, 0.f, 0.f, 0.f};

  const unsigned rb_off = (unsigned)(hi * 2048 + q) * 16u;
  int koff, voff, ldso;
  {
    int row = tid >> 3;
    int cc = (tid & 7) ^ (row & 7);
    koff = row * (DH * 2) + cc * 16;
    voff = row * (LSEQ * 2) + cc * 16;
    ldso = (wid * 64) * 16;
  }

  // ---- prologue: stage tile 0 (buf 0) ----
  gload_lds16(Kbh + koff, (char*)Ks[0] + ldso);
  gload_lds16(Kbh + koff + 4096, (char*)Ks[0] + ldso + 4096);
  gload_lds16(Vbh + voff, (char*)Vs[0] + ldso);
  gload_lds16(Vbh + voff + 131072, (char*)Vs[0] + ldso + 4096);
  __syncthreads();

  auto TILE = [&](int t, int buf, bool pref) {
    const char* rb_t = (const char*)RbX + (size_t)t * 262144;
    u32x4 rrA = *(const u32x4*)(rb_t + rb_off);
    u32x4 rrB = *(const u32x4*)(rb_t + 65536 + rb_off);

    if (pref) {
      const char* Kt = Kbh + (size_t)(t + 1) * (64 * DH * 2);
      const char* Vn = Vbh + (size_t)(t + 1) * (64 * 2);
      gload_lds16(Kt + koff, (char*)Ks[buf ^ 1] + ldso);
      gload_lds16(Kt + koff + 4096, (char*)Ks[buf ^ 1] + ldso + 4096);
      gload_lds16(Vn + voff, (char*)Vs[buf ^ 1] + ldso);
      gload_lds16(Vn + voff + 131072, (char*)Vs[buf ^ 1] + ldso + 4096);
    }

    // ---- S^T = K Q^T : first MFMA consumes shared zero C ----
    f32x16 sac[2];
    __builtin_amdgcn_s_setprio(1);
    {
      int r0 = l32, r1 = 32 + l32;
      bf8v kf0 = *(const bf8v*)((const char*)Ks[buf] + ((r0 * 128 + hi * 16) ^ ((r0 & 7) << 4)));
      bf8v kf1 = *(const bf8v*)((const char*)Ks[buf] + ((r1 * 128 + hi * 16) ^ ((r1 & 7) << 4)));
      sac[0] = __builtin_amdgcn_mfma_f32_32x32x16_bf16(kf0, qf[0], kz, 0, 0, 0);
      sac[1] = __builtin_amdgcn_mfma_f32_32x32x16_bf16(kf1, qf[0], kz, 0, 0, 0);
    }
    #pragma unroll
    for (int s = 1; s < 4; ++s) {
      #pragma unroll
      for (int kb2 = 0; kb2 < 2; ++kb2) {
        int row = kb2 * 32 + l32;
        bf8v kf = *(const bf8v*)((const char*)Ks[buf] +
                   ((row * 128 + s * 32 + hi * 16) ^ ((row & 7) << 4)));
        sac[kb2] = __builtin_amdgcn_mfma_f32_32x32x16_bf16(kf, qf[s], sac[kb2], 0, 0, 0);
      }
    }
    __builtin_amdgcn_s_setprio(0);

    // ---- column max: max3 chains, then 1 shuffle ----
    float mx;
    {
      float c0 = max3(sac[0][0], sac[0][1], sac[0][2]);
      float c1 = max3(sac[0][4], sac[0][5], sac[0][6]);
      float c2 = max3(sac[0][8], sac[0][9], sac[0][10]);
      float c3 = max3(sac[0][12], sac[0][13], sac[0][14]);
      c0 = max3(c0, sac[0][3], sac[1][0]);
      c1 = max3(c1, sac[0][7], sac[1][4]);
      c2 = max3(c2, sac[0][11], sac[1][8]);
      c3 = max3(c3, sac[0][15], sac[1][12]);
      c0 = max3(c0, sac[1][1], sac[1][2]);
      c1 = max3(c1, sac[1][5], sac[1][6]);
      c2 = max3(c2, sac[1][9], sac[1][10]);
      c3 = max3(c3, sac[1][13], sac[1][14]);
      c0 = max3(c0, sac[1][3], c1);
      c2 = max3(c2, sac[1][7], c3);
      mx = max3(c0, c2, fmaxf(sac[1][11], sac[1][15]));
      mx = fmaxf(mx, __shfl_xor(mx, 32));
    }

    // defer-max (T13)
    if (__any(mx > mrun + 8.f)) {
      float mnew = fmaxf(mrun, mx);
      float corr = fexp2(mrun - mnew);
      mrun = mnew;
      lrun *= corr;
      #pragma unroll
      for (int db = 0; db < 2; ++db)
        #pragma unroll
        for (int r = 0; r < 16; ++r) oacc[db][r] *= corr;
    }

    f32x2 m2; m2[0] = mrun; m2[1] = mrun;
    f32x2 ls2; ls2[0] = 0.f; ls2[1] = 0.f;

    // ---- per-16kv slice: packed exp*rb -> pack -> permlane -> PV mfma ----
    auto SLICE = [&](int s, const u32x4& rv) {
      const int blk = s >> 1, r0 = 8 * (s & 1);
      unsigned w[4];
      #pragma unroll
      for (int i = 0; i < 4; ++i) {
        f32x2 sv; sv[0] = sac[blk][r0 + 2 * i]; sv[1] = sac[blk][r0 + 2 * i + 1];
        sv = sv - m2;
        f32x2 pe; pe[0] = fexp2(sv[0]); pe[1] = fexp2(sv[1]);
        f32x2 rf;
        rf[0] = __uint_as_float(rv[i] << 16);
        rf[1] = __uint_as_float(rv[i] & 0xffff0000u);
        pe = pe * rf;
        ls2 = ls2 + pe;
        w[i] = cvt_pk_bf16(pe[0], pe[1]);
      }
      pl32swap(w[0], w[2]);
      pl32swap(w[1], w[3]);
      union { unsigned u[4]; bf8v v; } pf;
      pf.u[0] = w[0]; pf.u[1] = w[1]; pf.u[2] = w[2]; pf.u[3] = w[3];
      #pragma unroll
      for (int db = 0; db < 2; ++db) {
        int row = db * 32 + l32;
        bf8v vf = *(const bf8v*)((const char*)Vs[buf] +
                   ((row * 128 + s * 32 + hi * 16) ^ ((row & 7) << 4)));
        oacc[db] = __builtin_amdgcn_mfma_f32_32x32x16_bf16(vf, pf.v, oacc[db], 0, 0, 0);
      }
    };
    SLICE(0, rrA);
    rrA = *(const u32x4*)(rb_t + 131072 + rb_off);
    SLICE(1, rrB);
    rrB = *(const u32x4*)(rb_t + 196608 + rb_off);
    SLICE(2, rrA);
    SLICE(3, rrB);
    lrun += ls2[0] + ls2[1];
    __syncthreads();
  };

  for (int tp = 0; tp < 16; ++tp) {
    TILE(2 * tp,     0, true);
    TILE(2 * tp + 1, 1, tp != 15);
  }

  // ---- epilogue ----
  lrun += __shfl_xor(lrun, 32);
  float inv = 1.f / lrun;
  #pragma unroll
  for (int db = 0; db < 2; ++db)
    #pragma unroll
    for (int u = 0; u < 4; ++u) {
      u32x2 w;
      w[0] = cvt_pk_bf16(oacc[db][4 * u + 0] * inv, oacc[db][4 * u + 1] * inv);
      w[1] = cvt_pk_bf16(oacc[db][4 * u + 2] * inv, oacc[db][4 * u + 3] * inv);
      int d = db * 32 + u * 8 + hi * 4;
      *(u32x2*)(AO + (size_t)(b * LSEQ + q) * DIM + h * DH + d) = w;
    }
}

// ---------------- output projection + residual (plain grid mapping) ----------------
__global__ __launch_bounds__(256) void k_gemm_proj(
    const unsigned short* __restrict__ A, const unsigned short* __restrict__ W,
    const float* __restrict__ res, float* __restrict__ out) {
  __shared__ unsigned short As[128 * 64];
  __shared__ unsigned short Bs[128 * 64];
  f32x4 acc[4][4];
  f32x4 z = {0.f, 0.f, 0.f, 0.f};
  #pragma unroll
  for (int mi = 0; mi < 4; ++mi)
    #pragma unroll
    for (int ni = 0; ni < 4; ++ni) acc[mi][ni] = z;

  const int m0 = blockIdx.x * 128, n0 = blockIdx.y * 128;
  gemm_core(A, W, m0, n0, As, Bs, acc);

  const int tid = threadIdx.x;
  const int lane = tid & 63, wid = tid >> 6;
  const int g = lane >> 4, lq = lane & 15;
  const int wr = wid >> 1, wc = wid & 1;
  #pragma unroll
  for (int mi = 0; mi < 4; ++mi)
    #pragma unroll
    for (int ni = 0; ni < 4; ++ni) {
      int m = m0 + wr * 64 + mi * 16 + g * 4;
      int n = n0 + wc * 64 + ni * 16 + lq;
      #pragma unroll
      for (int r = 0; r < 4; ++r) {
        int idx = (m + r) * 1024 + n;
        out[idx] = acc[mi][ni][r] + res[idx];
      }
    }
}

// ---------------- in-place LayerNorm on d_out ----------------
__global__ __launch_bounds__(256) void k_ln(float* __restrict__ x,
                                            const float* __restrict__ gamma,
                                            const float* __restrict__ bias) {
  const int row = blockIdx.x;
  const int tid = threadIdx.x;
  float* xr = x + (size_t)row * 1024;
  f32x4 v = *(f32x4*)(xr + tid * 4);
  float s = v[0] + v[1] + v[2] + v[3];
  float ss = v[0] * v[0] + v[1] * v[1] + v[2] * v[2] + v[3] * v[3];
  #pragma unroll
  for (int off = 1; off < 64; off <<= 1) {
    s += __shfl_xor(s, off);
    ss += __shfl_xor(ss, off);
  }
  __shared__ float red[8];
  const int lane = tid & 63, wid = tid >> 6;
  if (lane == 0) { red[wid] = s; red[wid + 4] = ss; }
  __syncthreads();
  s = red[0] + red[1] + red[2] + red[3];
  ss = red[4] + red[5] + red[6] + red[7];
  float mu = s * (1.f / 1024.f);
  float var = ss * (1.f / 1024.f) - mu * mu;
  float rs = rsqrtf(var + 1e-5f);
  f32x4 gm = *(const f32x4*)(gamma + tid * 4);
  f32x4 bi = *(const f32x4*)(bias + tid * 4);
  f32x4 o;
  #pragma unroll
  for (int j = 0; j < 4; ++j) o[j] = (v[j] - mu) * rs * gm[j] + bi[j];
  *(f32x4*)(xr + tid * 4) = o;
}

extern "C" void kernel_launch(void* const* d_in, const int* in_sizes, int n_in,
                              void* d_out, int out_size, void* d_ws, size_t ws_size,
                              hipStream_t stream) {
  const float* tokens = (const float*)d_in[0];
  const float* R      = (const float*)d_in[1];
  const float* Wq     = (const float*)d_in[2];
  const float* Wk     = (const float*)d_in[3];
  const float* Wv     = (const float*)d_in[4];
  const float* Wp     = (const float*)d_in[5];
  const float* beta   = (const float*)d_in[6];
  const float* gamma  = (const float*)d_in[7];
  const float* bias   = (const float*)d_in[8];
  float* out = (float*)d_out;
  char* ws = (char*)d_ws;

  unsigned short* tok_bf = (unsigned short*)(ws);                 // 16,777,216 B
  unsigned short* wqkv   = (unsigned short*)(ws + 16777216);      //  8,388,608 B (Wq,Wk,Wv,Wp)
  u16x4*          rbx    = (u16x4*)(ws + 25165824);               //  8,388,608 B
  unsigned short* qb     = (unsigned short*)(ws + 41943040);      // 16,777,216 B
  unsigned short* kb     = (unsigned short*)(ws + 58720256);      // 16,777,216 B
  unsigned short* vt     = (unsigned short*)(ws + 75497472);      // 16,777,216 B
  unsigned short* wp     = wqkv + 3 * DIM * DIM;
  unsigned short* ao     = tok_bf;  // reuse: tok_bf dead after QKV GEMM

  k_prep<<<6656, 256, 0, stream>>>(tokens, tok_bf, Wq, Wk, Wv, Wp, wqkv, R, beta, rbx);

  k_gemm_qkv<<<dim3(64, 24), 256, 0, stream>>>(tok_bf, wqkv, qb, kb, vt);
  k_attn<<<dim3(16, 64), 256, 0, stream>>>(qb, kb, vt, (const unsigned short*)rbx, ao);
  k_gemm_proj<<<dim3(64, 8), 256, 0, stream>>>(ao, wp, tokens, out);
  k_ln<<<8192, 256, 0, stream>>>(out, gamma, bias);
}